// Round 2
// baseline (421.399 us; speedup 1.0000x reference)
//
#include <hip/hip_runtime.h>

#define B 8
#define K 16
#define H 224
#define W 224
#define PH 232
#define PW 232
#define WIN 9
#define NP (B * H * W)            // 401408 pixels

typedef float vf4 __attribute__((ext_vector_type(4), aligned(4)));
typedef float vf4a __attribute__((ext_vector_type(4)));
typedef const __attribute__((address_space(1))) char gchar;
typedef __attribute__((address_space(3))) char lchar;

// ---------------- Kernel T: weight [pix][81] -> wT [81][pix] ----------------
// Pure-BW tiled transpose: coalesced nt float4 reads, LDS [81][132] (b128-able
// rows, stride!=0 mod 32), coalesced nt float4 writes.
__global__ __launch_bounds__(256) void ncuts_transpose(
    const float* __restrict__ wgt, float* __restrict__ wT)
{
    __shared__ float t[81][132];
    const int  pb    = blockIdx.x;            // 3136 blocks x 128 pixels
    const long gbase = (long)pb * 10368;      // 128 px * 81 floats
    const int  tid   = threadIdx.x;

#pragma unroll 1
    for (int it = 0; it < 11; ++it) {
        const int f4 = it * 256 + tid;        // float4 idx in tile, < 2592
        if (f4 < 2592) {
            vf4a v = __builtin_nontemporal_load((const vf4a*)(wgt + gbase + (long)f4 * 4));
            const int idx = f4 * 4;
#pragma unroll
            for (int tt = 0; tt < 4; ++tt) {
                const int id = idx + tt;
                const int px = id / 81;
                const int c  = id - px * 81;
                t[c][px] = ((const float*)&v)[tt];
            }
        }
    }
    __syncthreads();
#pragma unroll 1
    for (int it = 0; it < 11; ++it) {
        const int o = it * 256 + tid;         // c*32 + j, < 2592
        if (o < 2592) {
            const int c = o >> 5;
            const int j = o & 31;
            vf4a v = *(const vf4a*)&t[c][4 * j];
            __builtin_nontemporal_store(v, (vf4a*)(wT + (long)c * NP + pb * 128 + 4 * j));
        }
    }
}

// ---------------- Kernel M: main, all 16 k per block ----------------
// Block: 256 thr = q(8) x kg(8) x rg(4 waves); tile = 8 out-rows x 32 px x 16 k.
// Thread: 4 px x 2 out-rows x 2 k. Each wv4[9] weight batch feeds 2 k (144
// FMAs) -> global load instrs halved vs K_PER=1, and weight fetched once per
// tile total (no ks-partner re-reads). LDS: 16 padded k-planes, row stride 44,
// plane stride 708 (1416 floats per kg pair == 8 mod 32 -> worst 2-way, free).
#define PSTR 708                              // 16 rows * 44 + 4 pad
#define RSTR 44

__global__ __launch_bounds__(256, 3) void ncuts_main16(
    const float* __restrict__ seg,
    const float* __restrict__ padded,
    const float* __restrict__ wT,
    const float* __restrict__ sumw,
    float* __restrict__ ws)
{
    __shared__ float pad_lds[16 * PSTR];      // 45.3 KB
    __shared__ float red[4][16][2];

    const int tid = threadIdx.x;
    const int bid = blockIdx.x;               // b + 8*(wt + 7*ht)
    const int b   = bid & 7;                  // XCD x owns batch b
    const int rest = bid >> 3;                // 0..195
    const int ht  = rest / 7;
    const int wt  = rest - ht * 7;
    const int h0 = ht * 8, w0 = wt * 32;

    // ---- stage padded: 16 planes x 16 rows x 40 floats (stride 44) ----
    // reg-staged (global->VGPR->LDS) so we can use the conflict-free layout.
#pragma unroll
    for (int i = 0; i < 10; ++i) {
        const int f   = tid + 256 * i;        // < 2560 float4s
        const int k   = f / 160;
        const int rem = f - k * 160;
        const int r   = rem / 10;
        const int c   = rem - r * 10;
        vf4a v = *(const vf4a*)(padded +
            (((long)(b * K + k) * PH + (h0 + r)) * PW + (w0 + 4 * c)));
        *(vf4a*)&pad_lds[k * PSTR + r * RSTR + 4 * c] = v;
    }
    __syncthreads();

    const int lane = tid & 63;
    const int q    = lane & 7;                // px group (4 px)
    const int kg   = lane >> 3;               // 0..7 -> k pair
    const int rg   = tid >> 6;                // wave = 2 out-rows
    const int hb   = h0 + rg * 2;
    const long pix0 = (long)(b * H + hb) * W + w0 + 4 * q;

    float acc[2][2][4];                       // [rp][kk][p]
#pragma unroll
    for (int rp = 0; rp < 2; ++rp)
#pragma unroll
        for (int kk = 0; kk < 2; ++kk)
#pragma unroll
            for (int p = 0; p < 4; ++p) acc[rp][kk][p] = 0.f;

#pragma unroll 2
    for (int prl = 0; prl < 10; ++prl) {      // padded row local to thread
        // window registers for both k planes of this thread
        float winK[2][12];
#pragma unroll
        for (int kk = 0; kk < 2; ++kk) {
            const float* lb = &pad_lds[(kg * 2 + kk) * PSTR + (rg * 2 + prl) * RSTR + 4 * q];
            vf4a a0 = *(const vf4a*)(lb);
            vf4a a1 = *(const vf4a*)(lb + 4);
            vf4a a2 = *(const vf4a*)(lb + 8);
#pragma unroll
            for (int p = 0; p < 4; ++p) {
                winK[kk][p]     = ((const float*)&a0)[p];
                winK[kk][p + 4] = ((const float*)&a1)[p];
                winK[kk][p + 8] = ((const float*)&a2)[p];
            }
        }

        const bool v0 = (prl <= 8);           // rp=0, m=prl
        const bool v1 = (prl >= 1);           // rp=1, m=prl-1
        vf4a wv0[9], wv1[9];
        if (v0) {
            const float* wr = wT + (long)(prl * 9) * NP + pix0;
#pragma unroll
            for (int n = 0; n < 9; ++n) wv0[n] = *(const vf4a*)(wr + (long)n * NP);
        }
        if (v1) {
            const float* wr = wT + (long)((prl - 1) * 9) * NP + pix0 + W;
#pragma unroll
            for (int n = 0; n < 9; ++n) wv1[n] = *(const vf4a*)(wr + (long)n * NP);
        }
        if (v0) {
#pragma unroll
            for (int n = 0; n < 9; ++n)
#pragma unroll
                for (int kk = 0; kk < 2; ++kk)
#pragma unroll
                    for (int p = 0; p < 4; ++p)
                        acc[0][kk][p] = fmaf(winK[kk][p + n], ((const float*)&wv0[n])[p], acc[0][kk][p]);
        }
        if (v1) {
#pragma unroll
            for (int n = 0; n < 9; ++n)
#pragma unroll
                for (int kk = 0; kk < 2; ++kk)
#pragma unroll
                    for (int p = 0; p < 4; ++p)
                        acc[1][kk][p] = fmaf(winK[kk][p + n], ((const float*)&wv1[n])[p], acc[1][kk][p]);
        }
    }

    // ---- epilogue: assocA/assocV partials ----
    float aA[2] = {0.f, 0.f}, aV[2] = {0.f, 0.f};
#pragma unroll
    for (int rp = 0; rp < 2; ++rp) {
        const vf4a sw4 = __builtin_nontemporal_load((const vf4a*)(sumw + pix0 + rp * W));
#pragma unroll
        for (int kk = 0; kk < 2; ++kk) {
            const int k = kg * 2 + kk;
            const float* sp = seg + ((long)(b * K + k) * H + hb + rp) * W + w0 + 4 * q;
            const vf4a s4 = __builtin_nontemporal_load((const vf4a*)sp);
#pragma unroll
            for (int p = 0; p < 4; ++p) {
                aA[kk] = fmaf(acc[rp][kk][p], ((const float*)&s4)[p], aA[kk]);
                aV[kk] = fmaf(((const float*)&sw4)[p], ((const float*)&s4)[p], aV[kk]);
            }
        }
    }
    // reduce over q (lane bits 0-2); kg lanes survive
#pragma unroll
    for (int d = 1; d <= 4; d <<= 1) {
#pragma unroll
        for (int kk = 0; kk < 2; ++kk) {
            aA[kk] += __shfl_xor(aA[kk], d);
            aV[kk] += __shfl_xor(aV[kk], d);
        }
    }
    if (q == 0) {
#pragma unroll
        for (int kk = 0; kk < 2; ++kk) {
            red[rg][kg * 2 + kk][0] = aA[kk];
            red[rg][kg * 2 + kk][1] = aV[kk];
        }
    }
    __syncthreads();
    if (tid < 32) {
        const int k  = tid >> 1;
        const int ab = tid & 1;
        const float v = red[0][k][ab] + red[1][k][ab] + red[2][k][ab] + red[3][k][ab];
        atomicAdd(&ws[ab * 128 + b * 16 + k], v);
    }
}

// ---------------- Fallback (R5 kernel, used if ws too small) ----------------
#define HT 16
#define WT 32
#define KT 4
#define ROWS (HT + 8)
#define LDSW 64
#define NWT (W / WT)
#define NB5 (B * (H / HT) * NWT * (K / KT))

__global__ __launch_bounds__(128, 3) void ncuts_fb(
    const float* __restrict__ seg, const float* __restrict__ padded,
    const float* __restrict__ weight, const float* __restrict__ sumw,
    float* __restrict__ ws)
{
    __shared__ float lds[KT][ROWS][LDSW];
    const int tid = threadIdx.x, lane = tid & 63, wv = tid >> 6;
    const int b = blockIdx.x & 7, s = blockIdx.x >> 3;
    const int kq = s & 3, tile = s >> 2;
    const int ht = tile / NWT, wt = tile - ht * NWT;
    const int k0 = kq * KT, h0 = ht * HT, w0 = wt * WT;
    {
        const int rb = lane >> 4, c = lane & 15, cc = c < 10 ? c : 9;
#pragma unroll
        for (int i = 0; i < 12; ++i) {
            const int j = wv * 12 + i, kk = j / 6, batch = j - kk * 6;
            const float* g = padded + (((long)(b * K + k0 + kk) * PH + (h0 + batch * 4 + rb)) * PW + (w0 + 4 * cc));
            __builtin_amdgcn_global_load_lds((gchar*)g, (lchar*)&lds[kk][batch * 4][0], 16, 0, 0);
        }
    }
    __syncthreads();
    const int r = tid >> 3, q = tid & 7, h = h0 + r, wp = w0 + 4 * q;
    const long pix = (long)(b * H + h) * W + wp;
    const float* wbase = weight + pix * 81;
    float acc[KT][4];
#pragma unroll
    for (int kk = 0; kk < KT; ++kk)
#pragma unroll
        for (int p = 0; p < 4; ++p) acc[kk][p] = 0.f;
#pragma unroll 1
    for (int m = 0; m < WIN; ++m) {
        float wr[4][WIN];
#pragma unroll
        for (int p = 0; p < 4; ++p) {
            const float* wpt = wbase + (long)p * 81 + m * 9;
            vf4 wa = *(const vf4*)wpt; vf4 wb = *(const vf4*)(wpt + 4);
            float wc = wpt[8];
            wr[p][0] = wa.x; wr[p][1] = wa.y; wr[p][2] = wa.z; wr[p][3] = wa.w;
            wr[p][4] = wb.x; wr[p][5] = wb.y; wr[p][6] = wb.z; wr[p][7] = wb.w;
            wr[p][8] = wc;
        }
#pragma unroll
        for (int kk = 0; kk < KT; ++kk) {
            const float4* pr = (const float4*)&lds[kk][r + m][4 * q];
            float4 a0 = pr[0], a1 = pr[1], a2 = pr[2];
            float win[12] = {a0.x, a0.y, a0.z, a0.w, a1.x, a1.y, a1.z, a1.w, a2.x, a2.y, a2.z, a2.w};
#pragma unroll
            for (int p = 0; p < 4; ++p)
#pragma unroll
                for (int n = 0; n < WIN; ++n)
                    acc[kk][p] = fmaf(win[p + n], wr[p][n], acc[kk][p]);
        }
    }
    const vf4a sw4 = __builtin_nontemporal_load((const vf4a*)(sumw + pix));
    const float swv[4] = {sw4.x, sw4.y, sw4.z, sw4.w};
#pragma unroll
    for (int kk = 0; kk < KT; ++kk) {
        const float* sp = seg + ((long)(b * K + k0 + kk) * H + h) * W + wp;
        const vf4a s4 = __builtin_nontemporal_load((const vf4a*)sp);
        float a = 0.f, v = 0.f;
#pragma unroll
        for (int p = 0; p < 4; ++p) {
            a = fmaf(acc[kk][p], ((const float*)&s4)[p], a);
            v = fmaf(swv[p], ((const float*)&s4)[p], v);
        }
#pragma unroll
        for (int off = 32; off > 0; off >>= 1) { a += __shfl_xor(a, off); v += __shfl_xor(v, off); }
        if (lane == 0) { atomicAdd(&ws[b * K + k0 + kk], a); atomicAdd(&ws[128 + b * K + k0 + kk], v); }
    }
}

__global__ void ncuts_final(const float* __restrict__ ws,
                            const int* __restrict__ ncut_k,
                            float* __restrict__ out)
{
    const int t = threadIdx.x;          // 128 threads: t = b*16 + k
    const int b = t >> 4;
    const int k = t & 15;
    float r = ws[b * K + k] / ws[128 + b * K + k];
#pragma unroll
    for (int off = 1; off < 16; off <<= 1) r += __shfl_xor(r, off, 16);
    if (k == 0) out[b] = (float)(*ncut_k) - r;
}

extern "C" void kernel_launch(void* const* d_in, const int* in_sizes, int n_in,
                              void* d_out, int out_size, void* d_ws, size_t ws_size,
                              hipStream_t stream) {
    (void)in_sizes; (void)n_in; (void)out_size;
    const float* seg    = (const float*)d_in[0];
    const float* padded = (const float*)d_in[1];
    const float* weight = (const float*)d_in[2];
    const float* sumw   = (const float*)d_in[3];
    const int*   nk     = (const int*)d_in[5];
    float* ws  = (float*)d_ws;
    float* out = (float*)d_out;

    hipMemsetAsync(ws, 0, 2 * B * K * sizeof(float), stream);

    const size_t need = 1024 + (size_t)81 * NP * 4;   // accumulators + wT
    if (ws_size >= need) {
        float* wT = ws + 256;
        ncuts_transpose<<<NP / 128, 256, 0, stream>>>(weight, wT);
        ncuts_main16<<<8 * 28 * 7, 256, 0, stream>>>(seg, padded, wT, sumw, ws);
    } else {
        ncuts_fb<<<NB5, 128, 0, stream>>>(seg, padded, weight, sumw, ws);
    }
    ncuts_final<<<1, 128, 0, stream>>>(ws, nk, out);
}

// Round 3
// 309.157 us; speedup vs baseline: 1.3631x; 1.3631x over previous
//
#include <hip/hip_runtime.h>

#define B 8
#define K 16
#define H 224
#define W 224
#define PH 232
#define PW 232
#define WIN 9
#define NP (B * H * W)            // 401408 pixels

typedef float vf4 __attribute__((ext_vector_type(4), aligned(4)));
typedef float vf4a __attribute__((ext_vector_type(4)));
typedef const __attribute__((address_space(1))) char gchar;
typedef __attribute__((address_space(3))) char lchar;

// ---------------- Kernel T: weight [pix][81] -> wT [81][pix] ----------------
__global__ __launch_bounds__(256) void ncuts_transpose(
    const float* __restrict__ wgt, float* __restrict__ wT)
{
    __shared__ float t[81][132];
    const int  pb    = blockIdx.x;            // 3136 blocks x 128 pixels
    const long gbase = (long)pb * 10368;      // 128 px * 81 floats
    const int  tid   = threadIdx.x;

#pragma unroll 1
    for (int it = 0; it < 11; ++it) {
        const int f4 = it * 256 + tid;        // float4 idx in tile, < 2592
        if (f4 < 2592) {
            vf4a v = __builtin_nontemporal_load((const vf4a*)(wgt + gbase + (long)f4 * 4));
            const int idx = f4 * 4;
#pragma unroll
            for (int tt = 0; tt < 4; ++tt) {
                const int id = idx + tt;
                const int px = id / 81;
                const int c  = id - px * 81;
                t[c][px] = ((const float*)&v)[tt];
            }
        }
    }
    __syncthreads();
#pragma unroll 1
    for (int it = 0; it < 11; ++it) {
        const int o = it * 256 + tid;         // c*32 + j, < 2592
        if (o < 2592) {
            const int c = o >> 5;
            const int j = o & 31;
            vf4a v = *(const vf4a*)&t[c][4 * j];
            __builtin_nontemporal_store(v, (vf4a*)(wT + (long)c * NP + pb * 128 + 4 * j));
        }
    }
}

// ---------------- Kernel M: main, all 16 k per block ----------------
// Block: 256 thr = q(8) x kg(8) x rg(4 waves); tile = 8 out-rows x 32 px x 16 k.
// Thread: 4 px x 2 out-rows x 2 k. One wv[9] weight batch feeds 2 k (72 FMAs,
// 8:1 FMA:load) and weight is fetched once per tile (no ks-partner re-reads).
// SPILL FIX vs R1: single wv[9] array, loaded AND consumed inside the same
// guarded block (mainT's proven spill-free codegen pattern), unroll 1.
// LDS: 16 padded k-planes, row stride 44, plane stride 708
// (1416 floats per kg step == 8 mod 32 -> worst 2-way conflict, free).
#define PSTR 708                              // 16 rows * 44 + 4 pad
#define RSTR 44

__global__ __launch_bounds__(256, 3) void ncuts_main16(
    const float* __restrict__ seg,
    const float* __restrict__ padded,
    const float* __restrict__ wT,
    const float* __restrict__ sumw,
    float* __restrict__ ws)
{
    __shared__ float pad_lds[16 * PSTR];      // 45.3 KB
    __shared__ float red[4][16][2];

    const int tid = threadIdx.x;
    const int bid = blockIdx.x;               // b + 8*(wt + 7*ht)
    const int b   = bid & 7;                  // XCD x owns batch b
    const int rest = bid >> 3;                // 0..195
    const int ht  = rest / 7;
    const int wt  = rest - ht * 7;
    const int h0 = ht * 8, w0 = wt * 32;

    // ---- stage padded: 16 planes x 16 rows x 40 floats (stride 44) ----
#pragma unroll
    for (int i = 0; i < 10; ++i) {
        const int f   = tid + 256 * i;        // < 2560 float4s
        const int k   = f / 160;
        const int rem = f - k * 160;
        const int r   = rem / 10;
        const int c   = rem - r * 10;
        vf4a v = *(const vf4a*)(padded +
            (((long)(b * K + k) * PH + (h0 + r)) * PW + (w0 + 4 * c)));
        *(vf4a*)&pad_lds[k * PSTR + r * RSTR + 4 * c] = v;
    }
    __syncthreads();

    const int lane = tid & 63;
    const int q    = lane & 7;                // px group (4 px)
    const int kg   = lane >> 3;               // 0..7 -> k pair
    const int rg   = tid >> 6;                // wave = 2 out-rows
    const int hb   = h0 + rg * 2;
    const long pix0 = (long)(b * H + hb) * W + w0 + 4 * q;

    float acc[2][2][4];                       // [rp][kk][p]
#pragma unroll
    for (int rp = 0; rp < 2; ++rp)
#pragma unroll
        for (int kk = 0; kk < 2; ++kk)
#pragma unroll
            for (int p = 0; p < 4; ++p) acc[rp][kk][p] = 0.f;

#pragma unroll 1
    for (int prl = 0; prl < 10; ++prl) {      // padded row local to thread
        // window registers for both k planes of this thread (6 ds_read_b128)
        float winK[2][12];
#pragma unroll
        for (int kk = 0; kk < 2; ++kk) {
            const float* lb = &pad_lds[(kg * 2 + kk) * PSTR + (rg * 2 + prl) * RSTR + 4 * q];
            vf4a a0 = *(const vf4a*)(lb);
            vf4a a1 = *(const vf4a*)(lb + 4);
            vf4a a2 = *(const vf4a*)(lb + 8);
#pragma unroll
            for (int p = 0; p < 4; ++p) {
                winK[kk][p]     = ((const float*)&a0)[p];
                winK[kk][p + 4] = ((const float*)&a1)[p];
                winK[kk][p + 8] = ((const float*)&a2)[p];
            }
        }

        if (prl <= 8) {                       // rp=0, tap row m = prl
            const float* wr = wT + (long)(prl * 9) * NP + pix0;
            vf4a wv[9];
#pragma unroll
            for (int n = 0; n < 9; ++n) wv[n] = *(const vf4a*)(wr + (long)n * NP);
#pragma unroll
            for (int n = 0; n < 9; ++n)
#pragma unroll
                for (int kk = 0; kk < 2; ++kk)
#pragma unroll
                    for (int p = 0; p < 4; ++p)
                        acc[0][kk][p] = fmaf(winK[kk][p + n], ((const float*)&wv[n])[p], acc[0][kk][p]);
        }
        if (prl >= 1) {                       // rp=1, tap row m = prl-1
            const float* wr = wT + (long)((prl - 1) * 9) * NP + pix0 + W;
            vf4a wv[9];
#pragma unroll
            for (int n = 0; n < 9; ++n) wv[n] = *(const vf4a*)(wr + (long)n * NP);
#pragma unroll
            for (int n = 0; n < 9; ++n)
#pragma unroll
                for (int kk = 0; kk < 2; ++kk)
#pragma unroll
                    for (int p = 0; p < 4; ++p)
                        acc[1][kk][p] = fmaf(winK[kk][p + n], ((const float*)&wv[n])[p], acc[1][kk][p]);
        }
    }

    // ---- epilogue: assocA/assocV partials ----
    float aA[2] = {0.f, 0.f}, aV[2] = {0.f, 0.f};
#pragma unroll
    for (int rp = 0; rp < 2; ++rp) {
        const vf4a sw4 = __builtin_nontemporal_load((const vf4a*)(sumw + pix0 + rp * W));
#pragma unroll
        for (int kk = 0; kk < 2; ++kk) {
            const int k = kg * 2 + kk;
            const float* sp = seg + ((long)(b * K + k) * H + hb + rp) * W + w0 + 4 * q;
            const vf4a s4 = __builtin_nontemporal_load((const vf4a*)sp);
#pragma unroll
            for (int p = 0; p < 4; ++p) {
                aA[kk] = fmaf(acc[rp][kk][p], ((const float*)&s4)[p], aA[kk]);
                aV[kk] = fmaf(((const float*)&sw4)[p], ((const float*)&s4)[p], aV[kk]);
            }
        }
    }
    // reduce over q (lane bits 0-2); kg lanes survive
#pragma unroll
    for (int d = 1; d <= 4; d <<= 1) {
#pragma unroll
        for (int kk = 0; kk < 2; ++kk) {
            aA[kk] += __shfl_xor(aA[kk], d);
            aV[kk] += __shfl_xor(aV[kk], d);
        }
    }
    if (q == 0) {
#pragma unroll
        for (int kk = 0; kk < 2; ++kk) {
            red[rg][kg * 2 + kk][0] = aA[kk];
            red[rg][kg * 2 + kk][1] = aV[kk];
        }
    }
    __syncthreads();
    if (tid < 32) {
        const int k  = tid >> 1;
        const int ab = tid & 1;
        const float v = red[0][k][ab] + red[1][k][ab] + red[2][k][ab] + red[3][k][ab];
        atomicAdd(&ws[ab * 128 + b * 16 + k], v);
    }
}

// ---------------- Fallback (R5 kernel, used if ws too small) ----------------
#define HT 16
#define WT 32
#define KT 4
#define ROWS (HT + 8)
#define LDSW 64
#define NWT (W / WT)
#define NB5 (B * (H / HT) * NWT * (K / KT))

__global__ __launch_bounds__(128, 3) void ncuts_fb(
    const float* __restrict__ seg, const float* __restrict__ padded,
    const float* __restrict__ weight, const float* __restrict__ sumw,
    float* __restrict__ ws)
{
    __shared__ float lds[KT][ROWS][LDSW];
    const int tid = threadIdx.x, lane = tid & 63, wv = tid >> 6;
    const int b = blockIdx.x & 7, s = blockIdx.x >> 3;
    const int kq = s & 3, tile = s >> 2;
    const int ht = tile / NWT, wt = tile - ht * NWT;
    const int k0 = kq * KT, h0 = ht * HT, w0 = wt * WT;
    {
        const int rb = lane >> 4, c = lane & 15, cc = c < 10 ? c : 9;
#pragma unroll
        for (int i = 0; i < 12; ++i) {
            const int j = wv * 12 + i, kk = j / 6, batch = j - kk * 6;
            const float* g = padded + (((long)(b * K + k0 + kk) * PH + (h0 + batch * 4 + rb)) * PW + (w0 + 4 * cc));
            __builtin_amdgcn_global_load_lds((gchar*)g, (lchar*)&lds[kk][batch * 4][0], 16, 0, 0);
        }
    }
    __syncthreads();
    const int r = tid >> 3, q = tid & 7, h = h0 + r, wp = w0 + 4 * q;
    const long pix = (long)(b * H + h) * W + wp;
    const float* wbase = weight + pix * 81;
    float acc[KT][4];
#pragma unroll
    for (int kk = 0; kk < KT; ++kk)
#pragma unroll
        for (int p = 0; p < 4; ++p) acc[kk][p] = 0.f;
#pragma unroll 1
    for (int m = 0; m < WIN; ++m) {
        float wr[4][WIN];
#pragma unroll
        for (int p = 0; p < 4; ++p) {
            const float* wpt = wbase + (long)p * 81 + m * 9;
            vf4 wa = *(const vf4*)wpt; vf4 wb = *(const vf4*)(wpt + 4);
            float wc = wpt[8];
            wr[p][0] = wa.x; wr[p][1] = wa.y; wr[p][2] = wa.z; wr[p][3] = wa.w;
            wr[p][4] = wb.x; wr[p][5] = wb.y; wr[p][6] = wb.z; wr[p][7] = wb.w;
            wr[p][8] = wc;
        }
#pragma unroll
        for (int kk = 0; kk < KT; ++kk) {
            const float4* pr = (const float4*)&lds[kk][r + m][4 * q];
            float4 a0 = pr[0], a1 = pr[1], a2 = pr[2];
            float win[12] = {a0.x, a0.y, a0.z, a0.w, a1.x, a1.y, a1.z, a1.w, a2.x, a2.y, a2.z, a2.w};
#pragma unroll
            for (int p = 0; p < 4; ++p)
#pragma unroll
                for (int n = 0; n < WIN; ++n)
                    acc[kk][p] = fmaf(win[p + n], wr[p][n], acc[kk][p]);
        }
    }
    const vf4a sw4 = __builtin_nontemporal_load((const vf4a*)(sumw + pix));
    const float swv[4] = {sw4.x, sw4.y, sw4.z, sw4.w};
#pragma unroll
    for (int kk = 0; kk < KT; ++kk) {
        const float* sp = seg + ((long)(b * K + k0 + kk) * H + h) * W + wp;
        const vf4a s4 = __builtin_nontemporal_load((const vf4a*)sp);
        float a = 0.f, v = 0.f;
#pragma unroll
        for (int p = 0; p < 4; ++p) {
            a = fmaf(acc[kk][p], ((const float*)&s4)[p], a);
            v = fmaf(swv[p], ((const float*)&s4)[p], v);
        }
#pragma unroll
        for (int off = 32; off > 0; off >>= 1) { a += __shfl_xor(a, off); v += __shfl_xor(v, off); }
        if (lane == 0) { atomicAdd(&ws[b * K + k0 + kk], a); atomicAdd(&ws[128 + b * K + k0 + kk], v); }
    }
}

__global__ void ncuts_final(const float* __restrict__ ws,
                            const int* __restrict__ ncut_k,
                            float* __restrict__ out)
{
    const int t = threadIdx.x;          // 128 threads: t = b*16 + k
    const int b = t >> 4;
    const int k = t & 15;
    float r = ws[b * K + k] / ws[128 + b * K + k];
#pragma unroll
    for (int off = 1; off < 16; off <<= 1) r += __shfl_xor(r, off, 16);
    if (k == 0) out[b] = (float)(*ncut_k) - r;
}

extern "C" void kernel_launch(void* const* d_in, const int* in_sizes, int n_in,
                              void* d_out, int out_size, void* d_ws, size_t ws_size,
                              hipStream_t stream) {
    (void)in_sizes; (void)n_in; (void)out_size;
    const float* seg    = (const float*)d_in[0];
    const float* padded = (const float*)d_in[1];
    const float* weight = (const float*)d_in[2];
    const float* sumw   = (const float*)d_in[3];
    const int*   nk     = (const int*)d_in[5];
    float* ws  = (float*)d_ws;
    float* out = (float*)d_out;

    hipMemsetAsync(ws, 0, 2 * B * K * sizeof(float), stream);

    const size_t need = 1024 + (size_t)81 * NP * 4;   // accumulators + wT
    if (ws_size >= need) {
        float* wT = ws + 256;
        ncuts_transpose<<<NP / 128, 256, 0, stream>>>(weight, wT);
        ncuts_main16<<<8 * 28 * 7, 256, 0, stream>>>(seg, padded, wT, sumw, ws);
    } else {
        ncuts_fb<<<NB5, 128, 0, stream>>>(seg, padded, weight, sumw, ws);
    }
    ncuts_final<<<1, 128, 0, stream>>>(ws, nk, out);
}

// Round 4
// 261.704 us; speedup vs baseline: 1.6102x; 1.1813x over previous
//
#include <hip/hip_runtime.h>

#define B 8
#define K 16
#define H 224
#define W 224
#define PH 232
#define PW 232
#define WIN 9
#define NP (B * H * W)            // 401408 pixels

typedef float vf4 __attribute__((ext_vector_type(4), aligned(4)));
typedef float vf4a __attribute__((ext_vector_type(4)));

// ---------------- Kernel M: direct-weight, all 16 k per block ----------------
// Replaces transpose+main16: weight read in native [pix][81] layout, once,
// streaming (each weight line consumed by exactly one block).
// Block: 256 thr = q(8) x kg(4) x r(8 waves of out-rows);
// tile = 8 out-rows x 32 px x 16 k. Thread: 4 px x 4 k x 1 out-row.
// Per prl (tap row m=prl, flat 0..8, NO branches):
//   12 ds_read_b128 (winK for 4 k) + 12 global loads (4 px x 9 taps)
//   -> 144 FMAs (12:1 FMA:load). acc/wt/winK all static-indexed, loaded and
//   consumed in the same straight-line region (R3's proven no-spill pattern).
// LDS: 16 padded k-planes, row stride 44, plane stride 708
// (4*PSTR == 16 mod 32 -> kg pairs 2-way alias only, free per m136).
#define PSTR 708                              // 16 rows * 44 + 4 pad
#define RSTR 44

__global__ __launch_bounds__(256, 3) void ncuts_dw(
    const float* __restrict__ seg,
    const float* __restrict__ padded,
    const float* __restrict__ weight,
    const float* __restrict__ sumw,
    float* __restrict__ ws)
{
    __shared__ float pad_lds[16 * PSTR];      // 45.3 KB
    __shared__ float red[4][16][2];

    const int tid = threadIdx.x;
    const int bid = blockIdx.x;               // b + 8*(wt + 7*ht)
    const int b   = bid & 7;                  // XCD x owns batch b
    const int rest = bid >> 3;                // 0..195
    const int ht  = rest / 7;
    const int wt  = rest - ht * 7;
    const int h0 = ht * 8, w0 = wt * 32;

    // ---- stage padded: 16 planes x 16 rows x 40 floats (stride 44) ----
#pragma unroll
    for (int i = 0; i < 10; ++i) {
        const int f   = tid + 256 * i;        // < 2560 float4s
        const int k   = f / 160;
        const int rem = f - k * 160;
        const int r   = rem / 10;
        const int c   = rem - r * 10;
        vf4a v = *(const vf4a*)(padded +
            (((long)(b * K + k) * PH + (h0 + r)) * PW + (w0 + 4 * c)));
        *(vf4a*)&pad_lds[k * PSTR + r * RSTR + 4 * c] = v;
    }
    __syncthreads();

    const int lane = tid & 63;
    const int q    = lane & 7;                // px group (4 px)
    const int kg   = (lane >> 3) & 3;         // k quad
    const int rr   = tid >> 5;                // 0..7 out-row (bit5 + wave id)
    const int h    = h0 + rr;
    const long pix0 = (long)(b * H + h) * W + w0 + 4 * q;
    const float* wbase = weight + pix0 * 81;  // 4 px rows, 81 floats apart

    float acc[4][4];                          // [kk][p]
#pragma unroll
    for (int kk = 0; kk < 4; ++kk)
#pragma unroll
        for (int p = 0; p < 4; ++p) acc[kk][p] = 0.f;

#pragma unroll 1
    for (int prl = 0; prl < 9; ++prl) {       // tap row m = prl
        // window registers for 4 k planes (12 ds_read_b128)
        float winK[4][12];
#pragma unroll
        for (int kk = 0; kk < 4; ++kk) {
            const float* lb = &pad_lds[(kg * 4 + kk) * PSTR + (rr + prl) * RSTR + 4 * q];
            vf4a a0 = *(const vf4a*)(lb);
            vf4a a1 = *(const vf4a*)(lb + 4);
            vf4a a2 = *(const vf4a*)(lb + 8);
#pragma unroll
            for (int p = 0; p < 4; ++p) {
                winK[kk][p]     = ((const float*)&a0)[p];
                winK[kk][p + 4] = ((const float*)&a1)[p];
                winK[kk][p + 8] = ((const float*)&a2)[p];
            }
        }
        // weight taps for 4 px (native layout, 4B-aligned loads)
        float wt_[4][9];
#pragma unroll
        for (int p = 0; p < 4; ++p) {
            const float* wp_ = wbase + (long)p * 81 + prl * 9;
            vf4 wa = *(const vf4*)wp_;
            vf4 wb = *(const vf4*)(wp_ + 4);
            const float w8 = wp_[8];
            wt_[p][0] = wa.x; wt_[p][1] = wa.y; wt_[p][2] = wa.z; wt_[p][3] = wa.w;
            wt_[p][4] = wb.x; wt_[p][5] = wb.y; wt_[p][6] = wb.z; wt_[p][7] = wb.w;
            wt_[p][8] = w8;
        }
#pragma unroll
        for (int n = 0; n < 9; ++n)
#pragma unroll
            for (int kk = 0; kk < 4; ++kk)
#pragma unroll
                for (int p = 0; p < 4; ++p)
                    acc[kk][p] = fmaf(winK[kk][p + n], wt_[p][n], acc[kk][p]);
    }

    // ---- epilogue: assocA/assocV partials (1 row, 4 px, 4 k) ----
    float aA[4], aV[4];
    {
        const vf4a sw4 = __builtin_nontemporal_load((const vf4a*)(sumw + pix0));
#pragma unroll
        for (int kk = 0; kk < 4; ++kk) {
            const int k = kg * 4 + kk;
            const float* sp = seg + ((long)(b * K + k) * H + h) * W + w0 + 4 * q;
            const vf4a s4 = __builtin_nontemporal_load((const vf4a*)sp);
            float a = 0.f, v = 0.f;
#pragma unroll
            for (int p = 0; p < 4; ++p) {
                a = fmaf(acc[kk][p], ((const float*)&s4)[p], a);
                v = fmaf(((const float*)&sw4)[p], ((const float*)&s4)[p], v);
            }
            aA[kk] = a; aV[kk] = v;
        }
    }
    // reduce over q (lane bits 0-2) and row-parity (bit 5); kg lanes survive
#pragma unroll
    for (int off = 0; off < 4; ++off) {
        const int d = (off < 3) ? (1 << off) : 32;
#pragma unroll
        for (int kk = 0; kk < 4; ++kk) {
            aA[kk] += __shfl_xor(aA[kk], d);
            aV[kk] += __shfl_xor(aV[kk], d);
        }
    }
    const int wv = tid >> 6;
    if ((lane & 39) == 0) {                   // lanes 0,8,16,24
#pragma unroll
        for (int kk = 0; kk < 4; ++kk) {
            red[wv][kg * 4 + kk][0] = aA[kk];
            red[wv][kg * 4 + kk][1] = aV[kk];
        }
    }
    __syncthreads();
    if (tid < 32) {
        const int k  = tid >> 1;
        const int ab = tid & 1;
        const float v = red[0][k][ab] + red[1][k][ab] + red[2][k][ab] + red[3][k][ab];
        atomicAdd(&ws[ab * 128 + b * 16 + k], v);
    }
}

__global__ void ncuts_final(const float* __restrict__ ws,
                            const int* __restrict__ ncut_k,
                            float* __restrict__ out)
{
    const int t = threadIdx.x;          // 128 threads: t = b*16 + k
    const int b = t >> 4;
    const int k = t & 15;
    float r = ws[b * K + k] / ws[128 + b * K + k];
#pragma unroll
    for (int off = 1; off < 16; off <<= 1) r += __shfl_xor(r, off, 16);
    if (k == 0) out[b] = (float)(*ncut_k) - r;
}

extern "C" void kernel_launch(void* const* d_in, const int* in_sizes, int n_in,
                              void* d_out, int out_size, void* d_ws, size_t ws_size,
                              hipStream_t stream) {
    (void)in_sizes; (void)n_in; (void)out_size; (void)ws_size;
    const float* seg    = (const float*)d_in[0];
    const float* padded = (const float*)d_in[1];
    const float* weight = (const float*)d_in[2];
    const float* sumw   = (const float*)d_in[3];
    const int*   nk     = (const int*)d_in[5];
    float* ws  = (float*)d_ws;
    float* out = (float*)d_out;

    hipMemsetAsync(ws, 0, 2 * B * K * sizeof(float), stream);
    ncuts_dw<<<8 * 28 * 7, 256, 0, stream>>>(seg, padded, weight, sumw, ws);
    ncuts_final<<<1, 128, 0, stream>>>(ws, nk, out);
}